// Round 6
// baseline (886.413 us; speedup 1.0000x reference)
//
#include <hip/hip_runtime.h>
#include <hip/hip_bf16.h>
#include <stdint.h>
#include <math.h>

typedef __bf16 bf16;
typedef __bf16 bf16x4 __attribute__((ext_vector_type(4)));
typedef __bf16 bf16x8 __attribute__((ext_vector_type(8)));
typedef float  f32x4  __attribute__((ext_vector_type(4)));
typedef float  f32x16 __attribute__((ext_vector_type(16)));

#define HIDDEN 4096
#define NH     32
#define NKV    8
#define HD     128
#define SEQ    2048
#define BATCH  2
#define NTOK   (BATCH*SEQ)   // 4096
#define QDIM   (NH*HD)       // 4096
#define KVDIM  (NKV*HD)      // 1024

#define NEGBIG (-3.0e38f)

__device__ __forceinline__ void gl_lds16(const bf16* g, bf16* l) {
    // async global->LDS, 16B/lane; LDS dest is wave-uniform base + lane*16
    __builtin_amdgcn_global_load_lds((__attribute__((address_space(1))) void*)g,
                                     (__attribute__((address_space(3))) void*)l,
                                     16, 0, 0);
}

// ---------------------------------------------------------------------------
// fp32 -> bf16 bulk convert, 8 elem/thread (two f32x4 loads, one 16B store)
// ---------------------------------------------------------------------------
__global__ __launch_bounds__(256)
void cvt_f32_bf16(const float* __restrict__ src, bf16* __restrict__ dst)
{
    const size_t i = ((size_t)blockIdx.x * 256 + threadIdx.x) * 8;
    f32x4 f0 = *(const f32x4*)(src + i);
    f32x4 f1 = *(const f32x4*)(src + i + 4);
    bf16x8 o;
    #pragma unroll
    for (int j = 0; j < 4; ++j) { o[j] = (bf16)f0[j]; o[4+j] = (bf16)f1[j]; }
    *(bf16x8*)(dst + i) = o;
}

// ---------------------------------------------------------------------------
// GEMM: C[m][n] = sum_k A[m][k] * B[n][k]   (A,B bf16 row-major, B^T input)
// m97 pattern: 128x128 tile, BK=32, 4 waves 2x2.
// MODE 0: C bf16 row-major.  MODE 1: C fp32.  MODE 2: C^T into vt layout.
// MODE 3: merged K/V projection — B is [wk; wv] (2048 rows); cols <1024 go to
//   Cv (kbuf, row-major, stride KVDIM); cols >=1024 go transposed into Cv2
//   (vtb [b][dcol][s]).  512 blocks = 2/CU so the vmcnt(0)+barrier drain
//   overlaps across blocks (m114).
// ---------------------------------------------------------------------------
template<int MODE>
__global__ __launch_bounds__(256)
void gemm_bt(const bf16* __restrict__ A, const bf16* __restrict__ B,
             void* __restrict__ Cv, void* __restrict__ Cv2, int M, int N, int K)
{
    __shared__ bf16 sA[128*32];
    __shared__ bf16 sB[128*32];

    const int tid  = threadIdx.x;
    const int wave = tid >> 6;
    const int lane = tid & 63;
    const int l15  = lane & 15;
    const int quad = lane >> 4;
    const int m_blk = blockIdx.y * 128;
    const int n_blk = blockIdx.x * 128;
    const int wm = (wave >> 1) * 64;
    const int wn = (wave & 1) * 64;

    f32x4 acc[4][4] = {};

    const int rowInSeg = lane >> 2;        // 0..15
    const int colInSeg = (lane & 3) * 8;   // 0,8,16,24

    for (int k0 = 0; k0 < K; k0 += 32) {
        __syncthreads();   // previous iteration's readers done
        #pragma unroll
        for (int i = 0; i < 2; ++i) {
            int s = wave * 2 + i;          // 8 segments of 16 rows each
            const bf16* ga = A + (size_t)(m_blk + s*16 + rowInSeg) * K + k0 + colInSeg;
            gl_lds16(ga, sA + s*512);
            const bf16* gb = B + (size_t)(n_blk + s*16 + rowInSeg) * K + k0 + colInSeg;
            gl_lds16(gb, sB + s*512);
        }
        __syncthreads();   // drains vmcnt(0) before barrier -> data landed

        bf16x8 af[4], bfr[4];
        #pragma unroll
        for (int mi = 0; mi < 4; ++mi)
            af[mi] = *(const bf16x8*)(sA + (wm + mi*16 + l15)*32 + quad*8);
        #pragma unroll
        for (int ni = 0; ni < 4; ++ni)
            bfr[ni] = *(const bf16x8*)(sB + (wn + ni*16 + l15)*32 + quad*8);
        #pragma unroll
        for (int mi = 0; mi < 4; ++mi)
            #pragma unroll
            for (int ni = 0; ni < 4; ++ni)
                acc[mi][ni] = __builtin_amdgcn_mfma_f32_16x16x32_bf16(
                                  af[mi], bfr[ni], acc[mi][ni], 0, 0, 0);
    }

    #pragma unroll
    for (int mi = 0; mi < 4; ++mi) {
        #pragma unroll
        for (int ni = 0; ni < 4; ++ni) {
            const int col = n_blk + wn + ni*16 + l15;
            const int row0 = m_blk + wm + mi*16 + quad*4;
            if constexpr (MODE == 2) {
                const int bb = row0 >> 11;          // /SEQ
                const int ss = row0 & (SEQ - 1);
                bf16x4 pk;
                #pragma unroll
                for (int r = 0; r < 4; ++r) pk[r] = (bf16)acc[mi][ni][r];
                *(bf16x4*)((bf16*)Cv + ((size_t)bb * KVDIM + col) * SEQ + ss) = pk;
            } else if constexpr (MODE == 1) {
                #pragma unroll
                for (int r = 0; r < 4; ++r)
                    ((float*)Cv)[(size_t)(row0 + r) * N + col] = acc[mi][ni][r];
            } else if constexpr (MODE == 3) {
                if (n_blk < KVDIM) {
                    // K path: row-major bf16, stride KVDIM
                    #pragma unroll
                    for (int r = 0; r < 4; ++r)
                        ((bf16*)Cv)[(size_t)(row0 + r) * KVDIM + col] = (bf16)acc[mi][ni][r];
                } else {
                    // V path: transposed into vt layout [b][dcol][s]
                    const int vcol = col - KVDIM;
                    const int bb = row0 >> 11;
                    const int ss = row0 & (SEQ - 1);
                    bf16x4 pk;
                    #pragma unroll
                    for (int r = 0; r < 4; ++r) pk[r] = (bf16)acc[mi][ni][r];
                    *(bf16x4*)((bf16*)Cv2 + ((size_t)bb * KVDIM + vcol) * SEQ + ss) = pk;
                }
            } else {
                #pragma unroll
                for (int r = 0; r < 4; ++r)
                    ((bf16*)Cv)[(size_t)(row0 + r) * N + col] = (bf16)acc[mi][ni][r];
            }
        }
    }
}

// ---------------------------------------------------------------------------
// 256x256 8-phase pipelined GEMM (m201 template port, plain HIP).
// r6: ds_reads software-pipelined ONE PHASE AHEAD — each phase, after its
// lgkmcnt(0), issues the NEXT phase's fragment reads; they complete under the
// current phase's 16 MFMAs, so the next lgkmcnt(0) is ~free.  Requires a 2nd
// A-fragment set (afA/afB).  Counted vmcnt moves to P3/P7 (vmcnt(4)): drains
// exactly the 8 loads of the buffer whose reads are issued in P4/P8.
// Read-issue ledger (phase: MM operands | reads issued for):
//   pre-loop: issue afA=buf0.qm0, b0=buf0.qn0          (exposed once)
//   P1: MM(0,0,afA,b0) | b1 =buf0.qn1                   P5: MM(0,0,afA,b0) | b1 =buf1.qn1
//   P2: MM(0,1,afA,b1) | afB=buf0.qm1                   P6: MM(0,1,afA,b1) | afB=buf1.qm1
//   P3: MM(1,0,afB,b0) | -          [vmcnt(4): buf1 in] P7: MM(1,0,afB,b0) | -  [vmcnt(4): buf0' in]
//   P4: MM(1,1,afB,b1) | afA,b0=buf1 (valid: P3 drain)  P8: MM(1,1,afB,b1) | afA,b0=buf0' (if pre)
// Liveness: every reg set is dead >=1 phase before its re-read (checked all 8).
// Race: every LDS region's readers finish (lgkm0 at next MIDBAR) >=1 barrier
// before the stage that overwrites it (checked all stage/read pairs).
// Outstanding-load ledger (steady): 8,10,12 ->drain4, 6,8,10,12 ->drain4, 6,8.
// ---------------------------------------------------------------------------
#define LDB2(p, qn, dst) { const char* base_ = (const char*)sB[p]; \
    _Pragma("unroll") for (int ni = 0; ni < 2; ++ni) \
    _Pragma("unroll") for (int ks = 0; ks < 2; ++ks) \
        dst[ni][ks] = *(const bf16x8*)(base_ + (wn + (qn)*32 + ni*16 + l15)*128 \
                                      + ((ks*64 + quad*16) ^ kx)); }

#define LDA2(p, qm, dst) { const char* base_ = (const char*)sA[p]; \
    _Pragma("unroll") for (int mi = 0; mi < 4; ++mi) \
    _Pragma("unroll") for (int ks = 0; ks < 2; ++ks) \
        dst[mi][ks] = *(const bf16x8*)(base_ + (wm + (qm)*64 + mi*16 + l15)*128 \
                                      + ((ks*64 + quad*16) ^ kx)); }

#define MM2(qm, qn, a, bf) { \
    _Pragma("unroll") for (int mi = 0; mi < 4; ++mi) \
    _Pragma("unroll") for (int ni = 0; ni < 2; ++ni) \
    _Pragma("unroll") for (int ks = 0; ks < 2; ++ks) \
        acc[(qm)*4+mi][(qn)*2+ni] = __builtin_amdgcn_mfma_f32_16x16x32_bf16( \
            a[mi][ks], bf[ni][ks], acc[(qm)*4+mi][(qn)*2+ni], 0, 0, 0); }

#define MIDBAR() { __builtin_amdgcn_s_barrier(); \
    asm volatile("s_waitcnt lgkmcnt(0)" ::: "memory"); \
    __builtin_amdgcn_sched_barrier(0); \
    __builtin_amdgcn_s_setprio(1); }

#define ENDBAR() { __builtin_amdgcn_s_setprio(0); \
    __builtin_amdgcn_sched_barrier(0); \
    __builtin_amdgcn_s_barrier(); }

#define ENDBAR_VM(n) { __builtin_amdgcn_s_setprio(0); \
    __builtin_amdgcn_sched_barrier(0); \
    asm volatile("s_waitcnt vmcnt(" #n ")" ::: "memory"); \
    __builtin_amdgcn_s_barrier(); }

template<bool F32OUT>
__global__ __launch_bounds__(512)
void gemm256(const bf16* __restrict__ A, const bf16* __restrict__ B,
             void* __restrict__ Cv, int M, int N, int K)
{
    __shared__ bf16 sA[2][256*64];   // 64 KB
    __shared__ bf16 sB[2][256*64];   // 64 KB

    const int tid  = threadIdx.x;
    const int wave = tid >> 6;
    const int lane = tid & 63;
    const int l15  = lane & 15;
    const int quad = lane >> 4;
    const int m_blk = blockIdx.y * 256;
    const int n_blk = blockIdx.x * 256;
    const int wm = (wave >> 2) * 128;     // wave M offset (0/128)
    const int wn = (wave & 3) * 64;       // wave N offset (0/64/128/192)
    const int kx = (l15 & 7) << 4;        // read-side swizzle XOR (row&7)<<4

    const bf16* Ag = A + (size_t)m_blk * K;
    const bf16* Bg = B + (size_t)n_blk * K;

    // staging lane geometry: 8-lane groups cover one 128B row, cols permuted
    // by the swizzle involution (slot_g = slot_lds ^ (row&7)).
    const int rs  = lane >> 3;                     // row within 8-row group
    const int sg8 = ((lane & 7) ^ rs) * 8;         // pre-swizzled col (elems)

    f32x4 acc[8][4] = {};

    // stage A interleaved-half h of buffer p at k0 (2 x global_load_lds)
    auto stA = [&](int p, int h, int k0) {
        bf16* sb = sA[p];
        const int r0 = h*64 + wave*8;              // rows r0..r0+7
        const int r1 = r0 + 128;                   // rows r1..r1+7
        gl_lds16(Ag + (size_t)(r0 + rs)*K + k0 + sg8, sb + r0*64);
        gl_lds16(Ag + (size_t)(r1 + rs)*K + k0 + sg8, sb + r1*64);
    };
    // stage B qn-half h of buffer p at k0 (2 x global_load_lds)
    auto stB = [&](int p, int h, int k0) {
        bf16* sb = sB[p];
        #pragma unroll
        for (int j = 0; j < 2; ++j) {
            const int s  = j*8 + wave;             // segment 0..15
            const int rb = (s>>2)*64 + h*32 + (s&3)*8;
            gl_lds16(Bg + (size_t)(rb + rs)*K + k0 + sg8, sb + rb*64);
        }
    };

    bf16x8 afA[4][2], afB[4][2], b0[2][2], b1[2][2];

    // ---- prologue: tile0 all 4 halves, then tile1 {A-ih0, B-qn0, B-qn1}
    stA(0, 0, 0);  stA(0, 1, 0);  stB(0, 0, 0);  stB(0, 1, 0);
    stA(1, 0, 64); stB(1, 0, 64); stB(1, 1, 64);
    asm volatile("s_waitcnt vmcnt(6)" ::: "memory");   // tile0 landed
    __builtin_amdgcn_s_barrier();
    // pre-loop read issue: P1's operands (exposed once)
    LDA2(0, 0, afA); LDB2(0, 0, b0);

    const int niter = K >> 7;                      // K/128 (2 K-tiles/iter)
    for (int it = 0; it < niter; ++it) {
        const int kc  = it << 7;
        const bool pre = (it + 1 < niter);

        // ================= K-tile 2it (buf 0) =================
        // P1: MM(0,0); issue b1(buf0); stage buf1.A-ih1
        stA(1, 1, kc + 64);
        MIDBAR();
        LDB2(0, 1, b1);
        MM2(0, 0, afA, b0); ENDBAR();

        // P2: MM(0,1); issue afB(buf0.qm1); stage buf0'.A-ih0
        if (pre) stA(0, 0, kc + 128);
        MIDBAR();
        LDA2(0, 1, afB);
        MM2(0, 1, afA, b1); ENDBAR();

        // P3: MM(1,0); no issue; stage buf0'.B-qn0; drain buf1 (oldest 8)
        if (pre) stB(0, 0, kc + 128);
        MIDBAR();
        MM2(1, 0, afB, b0);
        if (pre) { ENDBAR_VM(4); } else { ENDBAR_VM(0); }

        // P4: MM(1,1); issue afA,b0 := buf1 (valid: P3 drain+barrier); stage buf0'.B-qn1
        if (pre) stB(0, 1, kc + 128);
        MIDBAR();
        LDA2(1, 0, afA); LDB2(1, 0, b0);
        MM2(1, 1, afB, b1); ENDBAR();

        // ================= K-tile 2it+1 (buf 1) =================
        // P5: MM(0,0); issue b1(buf1); stage buf0'.A-ih1
        if (pre) stA(0, 1, kc + 128);
        MIDBAR();
        LDB2(1, 1, b1);
        MM2(0, 0, afA, b0); ENDBAR();

        // P6: MM(0,1); issue afB(buf1.qm1); stage buf1'.A-ih0
        if (pre) stA(1, 0, kc + 192);
        MIDBAR();
        LDA2(1, 1, afB);
        MM2(0, 1, afA, b1); ENDBAR();

        // P7: MM(1,0); no issue; stage buf1'.B-qn0; drain buf0' (oldest 8)
        if (pre) stB(1, 0, kc + 192);
        MIDBAR();
        MM2(1, 0, afB, b0);
        if (pre) { ENDBAR_VM(4); } else { ENDBAR(); }

        // P8: MM(1,1); issue afA,b0 := buf0' (next tile) if pre; stage buf1'.B-qn1
        if (pre) stB(1, 1, kc + 192);
        MIDBAR();
        if (pre) { LDA2(0, 0, afA); LDB2(0, 0, b0); }
        MM2(1, 1, afB, b1); ENDBAR();
    }

    // ---- epilogue: acc[qm*4+mi][qn*2+ni] -> C
    #pragma unroll
    for (int ai = 0; ai < 8; ++ai) {
        const int row0 = m_blk + wm + (ai>>2)*64 + (ai&3)*16 + quad*4;
        #pragma unroll
        for (int bi = 0; bi < 4; ++bi) {
            const int col = n_blk + wn + (bi>>1)*32 + (bi&1)*16 + l15;
            if constexpr (F32OUT) {
                #pragma unroll
                for (int r = 0; r < 4; ++r)
                    ((float*)Cv)[(size_t)(row0 + r)*N + col] = acc[ai][bi][r];
            } else {
                #pragma unroll
                for (int r = 0; r < 4; ++r)
                    ((bf16*)Cv)[(size_t)(row0 + r)*N + col] = (bf16)acc[ai][bi][r];
            }
        }
    }
}

// ---------------------------------------------------------------------------
// Per-head LayerNorm + RoPE, in place on bf16 workspace. One wave per
// (token, head); lane j holds dims j and j+64 (the RoPE pair). w is fp32.
// ---------------------------------------------------------------------------
__global__ __launch_bounds__(256)
void ln_rope(bf16* __restrict__ buf, const float* __restrict__ w,
             const int* __restrict__ pos, int nh)
{
    const int id   = blockIdx.x * 4 + (threadIdx.x >> 6);
    const int lane = threadIdx.x & 63;
    const int t  = id / nh;
    const int hh = id - t * nh;

    bf16* p = buf + (size_t)t * nh * HD + hh * HD;
    float x1 = (float)p[lane];
    float x2 = (float)p[lane + 64];

    float s1 = x1 + x2, s2 = x1*x1 + x2*x2;
    #pragma unroll
    for (int m = 1; m < 64; m <<= 1) {
        s1 += __shfl_xor(s1, m);
        s2 += __shfl_xor(s2, m);
    }
    const float mean = s1 * (1.0f/128.0f);
    const float var  = s2 * (1.0f/128.0f) - mean*mean;
    const float rs   = rsqrtf(fmaxf(var, 0.0f) + 1e-5f);

    const float w1 = w[hh*HD + lane];
    const float w2 = w[hh*HD + lane + 64];
    const float xn1 = (x1 - mean) * rs * w1;
    const float xn2 = (x2 - mean) * rs * w2;

    const int s = t & (SEQ - 1);
    // inv_freq = 10000^(-lane/64) = exp(-lane * ln(10000)/64)
    const float ang = (float)pos[s] * __expf(-(float)lane * (9.210340371976184f/64.0f));
    const float c = cosf(ang), sn = sinf(ang);

    p[lane]      = (bf16)(xn1 * c - xn2 * sn);
    p[lane + 64] = (bf16)(xn2 * c + xn1 * sn);
}

// ---------------------------------------------------------------------------
// Flash attention, causal, GQA — 8-wave swapped-operand structure (m214 port)
//   block = 256 q rows (8 waves x 32), KV tile = 64, mfma_f32_32x32x16_bf16
//   QK^T computed as mfma(K,Q)  -> S^T : q on lane&31, kv on regs
//   PV   computed as mfma(Vt,P) -> O^T : q on lane&31, d  on regs
//   => softmax max/sum, O-rescale, l-division all lane-local; P never
//      touches LDS (cross-half exchange via shfl_xor(.,32), T12)
//   K and V^T staged to XOR-swizzled LDS (T2), double-buffered, reg-staged
//   issue-early/write-late (T14), one barrier per tile, setprio on MFMA (T5),
//   defer-max THR=8 in log2 domain (T13).
//   Causal balance: qt mirrored on batch so every CU's 2 resident blocks sum
//   to the same kv work (36 tile-units) — kills the 1.8x makespan tail.
//   NOTE: permlane32_swap attempt (r3) FAILED correctness — swap-direction
//   semantics unverified; exchange uses harness-verified shfl_xor form.
// ---------------------------------------------------------------------------
struct StReg { bf16x8 k0, k1, v0, v1; };

__device__ __forceinline__ StReg stage_load(const bf16* kgp, const bf16* vgp, int t)
{
    StReg r;
    const size_t ko = (size_t)t * 64 * KVDIM;
    r.k0 = *(const bf16x8*)(kgp + ko);
    r.k1 = *(const bf16x8*)(kgp + ko + 64);
    r.v0 = *(const bf16x8*)(vgp + t*64);
    r.v1 = *(const bf16x8*)(vgp + t*64 + 32);
    return r;
}

__device__ __forceinline__ void stage_write(bf16* dk, bf16* dv, const StReg& r,
                                            int krow, int kcb, int vrow, int vcb)
{
    // K: [64 rows][128 cols] bf16, row stride 256B, byte ^= (row&7)<<4
    *(bf16x8*)((char*)dk + krow*256 + ( kcb        ^ ((krow&7)<<4))) = r.k0;
    *(bf16x8*)((char*)dk + krow*256 + ((kcb + 128) ^ ((krow&7)<<4))) = r.k1;
    // V^T: [128 d][64 kv] bf16, row stride 128B, same involution
    *(bf16x8*)((char*)dv + vrow*128 + ( vcb        ^ ((vrow&7)<<4))) = r.v0;
    *(bf16x8*)((char*)dv + vrow*128 + ((vcb +  64) ^ ((vrow&7)<<4))) = r.v1;
}

__device__ __forceinline__ unsigned pk2(float x, float y)
{
    union { bf16 h[2]; unsigned u; } c;
    c.h[0] = (bf16)x; c.h[1] = (bf16)y;
    return c.u;
}

__global__ __launch_bounds__(512, 2)
void attn_fa(bf16* __restrict__ qob,        // [NTOK][QDIM], Q in / O out
             const bf16* __restrict__ kbp,  // [NTOK][KVDIM]
             const bf16* __restrict__ vtb)  // [B][KVDIM][SEQ]  (V transposed)
{
    __shared__ bf16 sK[2][64*128];   // 32 KB, swizzled
    __shared__ bf16 sV[2][128*64];   // 32 KB, swizzled

    const int tid  = threadIdx.x;
    const int wave = tid >> 6;
    const int lane = tid & 63;
    const int l31  = lane & 31;
    const int hi   = lane >> 5;

    const int b  = blockIdx.z;       // batch (2)
    // mirror qt on batch: co-resident block pair (x,b=0)+(x,b=1) has constant
    // total kv work -> balanced per-CU makespan under round-robin dispatch
    const int qt = b ? (gridDim.x - 1 - blockIdx.x) : blockIdx.x;
    const int h  = blockIdx.y;       // q head (32)
    const int hk = h >> 2;
    const int qbase = qt * 256;
    const int qw    = qbase + wave * 32;   // wave's first q row
    const int qrow  = qw + l31;            // this lane's q row

    // ---- Q fragments (B operand): lane holds Q[qrow][ks*16 + hi*8 + 0..7]
    bf16x8 qf[8];
    {
        const bf16* qp = qob + (size_t)(b*SEQ + qrow)*QDIM + h*HD + hi*8;
        #pragma unroll
        for (int ks = 0; ks < 8; ++ks)
            qf[ks] = *(const bf16x8*)(qp + ks*16);
    }

    f32x16 oacc[4] = {};             // O^T: q = lane&31, d = dblk*32 + crow(reg,hi)
    float m_i = NEGBIG, l_i = 0.0f;

    // staging geometry (512 threads, 2 x 16B per tile for each of K, V^T)
    const int krow = tid >> 3;             // 0..63
    const int kcb  = (tid & 7) * 16;       // byte col 0..112
    const int vrow = tid >> 2;             // 0..127
    const int vcb  = (tid & 3) * 16;       // byte col 0..48
    const bf16* kgp = kbp + (size_t)(b*SEQ + krow)*KVDIM + hk*HD + (tid & 7)*8;
    const bf16* vgp = vtb + ((size_t)(b*NKV + hk)*HD + vrow)*SEQ + (tid & 3)*8;

    const int ntiles = qt*4 + 4;
    const float SC = 0.08838834764831845f * 1.4426950408889634f;  // scale*log2e
    const int kx = (l31 & 7) << 4;         // read-side swizzle (rows ≡ l31 mod 8)

    // prologue: stage tile 0 into buffer 0
    {
        StReg r = stage_load(kgp, vgp, 0);
        stage_write(sK[0], sV[0], r, krow, kcb, vrow, vcb);
    }
    __syncthreads();

    int cur = 0;
    for (int t = 0; t < ntiles; ++t) {
        const int kv0 = t * 64;
        const bool hn = (t + 1 < ntiles);
        StReg nx;
        if (hn) nx = stage_load(kgp, vgp, t + 1);   // issue early (T14)

        if (kv0 <= qw + 31) {                       // skip fully-masked tiles
            // ---- S^T = K·Q^T : 16 mfma, kv on regs, q on lanes
            f32x16 sa0 = {}, sa1 = {};
            const char* kl = (const char*)sK[cur];
            __builtin_amdgcn_s_setprio(1);
            #pragma unroll
            for (int ks = 0; ks < 8; ++ks) {
                const int cb = ks*32 + hi*16;
                bf16x8 k0 = *(const bf16x8*)(kl + l31*256        + (cb ^ kx));
                bf16x8 k1 = *(const bf16x8*)(kl + l31*256 + 8192 + (cb ^ kx));
                sa0 = __builtin_amdgcn_mfma_f32_32x32x16_bf16(k0, qf[ks], sa0, 0, 0, 0);
                sa1 = __builtin_amdgcn_mfma_f32_32x32x16_bf16(k1, qf[ks], sa1, 0, 0, 0);
            }
            __builtin_amdgcn_s_setprio(0);

            // ---- scale (log2 domain) + causal mask on diagonal tiles
            float s[32];
            #pragma unroll
            for (int r = 0; r < 16; ++r) { s[r] = sa0[r]*SC; s[16+r] = sa1[r]*SC; }
            if (kv0 + 63 > qw) {
                #pragma unroll
                for (int j = 0; j < 32; ++j) {
                    const int kv = kv0 + (j>>4)*32 + (j&3) + ((j>>2)&3)*8 + hi*4;
                    if (kv > qrow) s[j] = NEGBIG;
                }
            }

            // ---- online softmax, lane-local (partner lane = other 32 kv)
            float mt = s[0];
            #pragma unroll
            for (int j = 1; j < 32; ++j) mt = fmaxf(mt, s[j]);
            mt = fmaxf(mt, __shfl_xor(mt, 32));
            if (__any(mt > m_i + 8.0f)) {           // defer-max (T13)
                const float mnew = fmaxf(m_i, mt);
                const float al = exp2f(m_i - mnew);
                m_i = mnew; l_i *= al;
                #pragma unroll
                for (int d = 0; d < 4; ++d)
                    #pragma unroll
                    for (int r = 0; r < 16; ++r) oacc[d][r] *= al;
            }
            float p[32]; float sum = 0.0f;
            #pragma unroll
            for (int j = 0; j < 32; ++j) { p[j] = exp2f(s[j] - m_i); sum += p[j]; }
            sum += __shfl_xor(sum, 32);
            l_i += sum;

            // ---- P -> bf16 B-fragments, cross-half exchange (T12 w/ shfl)
            // pb[ks][j] = P[q][ks*16 + hi*8 + j]; src idx base c = (ks>>1)*16+(ks&1)*8
            bf16x8 pb[4];
            #pragma unroll
            for (int ks = 0; ks < 4; ++ks) {
                const int c = (ks>>1)*16 + (ks&1)*8;
                const unsigned a0 = pk2(p[c+0], p[c+1]);
                const unsigned a1 = pk2(p[c+2], p[c+3]);
                const unsigned b0 = pk2(p[c+4], p[c+5]);
                const unsigned b1 = pk2(p[c+6], p[c+7]);
                const unsigned r0 = (unsigned)__shfl_xor((int)(hi ? a0 : b0), 32);
                const unsigned r1 = (unsigned)__shfl_xor((int)(hi ? a1 : b1), 32);
                union { unsigned u[4]; bf16x8 v; } fr;
                fr.u[0] = hi ? r0 : a0;
                fr.u[1] = hi ? r1 : a1;
                fr.u[2] = hi ? b0 : r0;
                fr.u[3] = hi ? b1 : r1;
                pb[ks] = fr.v;
            }

            // ---- O^T += V^T·P : 16 mfma, d on regs, q on lanes
            const char* vl = (const char*)sV[cur];
            __builtin_amdgcn_s_setprio(1);
            #pragma unroll
            for (int d = 0; d < 4; ++d) {
                #pragma unroll
                for (int ks = 0; ks < 4; ++ks) {
                    const int cb = ks*32 + hi*16;
                    bf16x8 vf = *(const bf16x8*)(vl + (d*32 + l31)*128 + (cb ^ kx));
                    oacc[d] = __builtin_amdgcn_mfma_f32_32x32x16_bf16(vf, pb[ks], oacc[d], 0, 0, 0);
                }
            }
            __builtin_amdgcn_s_setprio(0);
        }

        if (hn) stage_write(sK[cur^1], sV[cur^1], nx, krow, kcb, vrow, vcb);
        __syncthreads();
        cur ^= 1;
    }

    // ---- epilogue: O/l back into qob (q = lane&31 -> lane-local l)
    const float inv = 1.0f / l_i;
    bf16* op = qob + (size_t)(b*SEQ + qrow)*QDIM + h*HD + hi*4;
    #pragma unroll
    for (int d = 0; d < 4; ++d) {
        #pragma unroll
        for (int q2 = 0; q2 < 4; ++q2) {
            bf16x4 pk;
            #pragma unroll
            for (int r = 0; r < 4; ++r) pk[r] = (bf16)(oacc[d][q2*4 + r] * inv);
            *(bf16x4*)(op + d*32 + q2*8) = pk;   // d = d*32 + q2*8 + hi*4 + r
        }
    }
}

// ---------------------------------------------------------------------------
extern "C" void kernel_launch(void* const* d_in, const int* in_sizes, int n_in,
                              void* d_out, int out_size, void* d_ws, size_t ws_size,
                              hipStream_t stream)
{
    // fp32 inputs per the reference dtypes
    const float* hidden = (const float*)d_in[0];
    const int*   pos    = (const int*)d_in[1];
    const float* wq     = (const float*)d_in[2];
    const float* wk     = (const float*)d_in[3];
    const float* wv     = (const float*)d_in[4];
    const float* wo     = (const float*)d_in[5];
    const float* qw     = (const float*)d_in[6];
    const float* kw     = (const float*)d_in[7];

    // bf16 workspace, 128 MB total (wo reuses the dead wq slot)
    bf16* hb   = (bf16*)d_ws;                          // [NTOK][HIDDEN]  32MB
    bf16* wqb  = hb   + (size_t)NTOK*HIDDEN;           // [QDIM][HIDDEN]  32MB (wq, then wo)
    bf16* wkb  = wqb  + (size_t)QDIM*HIDDEN;           // [KVDIM][HIDDEN]  8MB
    bf16* wvb  = wkb  + (size_t)KVDIM*HIDDEN;          // [KVDIM][HIDDEN]  8MB (contiguous after wkb!)
    bf16* qbuf = wvb  + (size_t)KVDIM*HIDDEN;          // [NTOK][QDIM]    32MB (Q, then attn out)
    bf16* kbuf = qbuf + (size_t)NTOK*QDIM;             // [NTOK][KVDIM]    8MB
    bf16* vtb  = kbuf + (size_t)NTOK*KVDIM;            // [B][KVDIM][SEQ]  8MB
    float* out = (float*)d_out;                        // fp32 output

    const dim3 blk(256);

    // fp32 -> bf16 pre-conversion (each size divisible by 2048)
    cvt_f32_bf16<<<dim3(NTOK*HIDDEN/2048),  blk, 0, stream>>>(hidden, hb);
    cvt_f32_bf16<<<dim3(QDIM*HIDDEN/2048),  blk, 0, stream>>>(wq, wqb);
    cvt_f32_bf16<<<dim3(KVDIM*HIDDEN/2048), blk, 0, stream>>>(wk, wkb);
    cvt_f32_bf16<<<dim3(KVDIM*HIDDEN/2048), blk, 0, stream>>>(wv, wvb);

    // Q-proj: 4096x4096x4096 -> 8-phase 256^2 kernel (grid 16x16 = 256 blocks)
    gemm256<false><<<dim3(QDIM/256, NTOK/256), dim3(512), 0, stream>>>(hb, wqb, qbuf, NTOK, QDIM, HIDDEN);

    // K+V proj merged: B = [wk; wv] (contiguous, 2048 rows), grid 16x32 = 512
    // blocks = 2 blocks/CU. Epilogue splits: cols<1024 -> kbuf, else vtb^T.
    gemm_bt<3><<<dim3((2*KVDIM)/128, NTOK/128), blk, 0, stream>>>(hb, wkb, kbuf, vtb, NTOK, 2*KVDIM, HIDDEN);

    // wq slot is dead after the Q-GEMM; stream order makes this safe
    cvt_f32_bf16<<<dim3(QDIM*HIDDEN/2048), blk, 0, stream>>>(wo, wqb);

    ln_rope<<<dim3(NTOK*NH/4),  blk, 0, stream>>>(qbuf, qw, pos, NH);
    ln_rope<<<dim3(NTOK*NKV/4), blk, 0, stream>>>(kbuf, kw, pos, NKV);

    attn_fa<<<dim3(SEQ/256, NH, BATCH), dim3(512), 0, stream>>>(qbuf, kbuf, vtb);

    // out-proj: 4096x4096x4096, fp32 out -> 8-phase kernel
    gemm256<true><<<dim3(QDIM/256, NTOK/256), dim3(512), 0, stream>>>(qbuf, wqb, out, NTOK, QDIM, HIDDEN);
}

// Round 7
// 717.597 us; speedup vs baseline: 1.2353x; 1.2353x over previous
//
#include <hip/hip_runtime.h>
#include <hip/hip_bf16.h>
#include <stdint.h>
#include <math.h>

typedef __bf16 bf16;
typedef __bf16 bf16x4 __attribute__((ext_vector_type(4)));
typedef __bf16 bf16x8 __attribute__((ext_vector_type(8)));
typedef float  f32x4  __attribute__((ext_vector_type(4)));
typedef float  f32x16 __attribute__((ext_vector_type(16)));

#define HIDDEN 4096
#define NH     32
#define NKV    8
#define HD     128
#define SEQ    2048
#define BATCH  2
#define NTOK   (BATCH*SEQ)   // 4096
#define QDIM   (NH*HD)       // 4096
#define KVDIM  (NKV*HD)      // 1024

#define NEGBIG (-3.0e38f)

__device__ __forceinline__ void gl_lds16(const bf16* g, bf16* l) {
    // async global->LDS, 16B/lane; LDS dest is wave-uniform base + lane*16
    __builtin_amdgcn_global_load_lds((__attribute__((address_space(1))) void*)g,
                                     (__attribute__((address_space(3))) void*)l,
                                     16, 0, 0);
}

// ---------------------------------------------------------------------------
// fp32 -> bf16 bulk convert, 8 elem/thread (two f32x4 loads, one 16B store)
// ---------------------------------------------------------------------------
__global__ __launch_bounds__(256)
void cvt_f32_bf16(const float* __restrict__ src, bf16* __restrict__ dst)
{
    const size_t i = ((size_t)blockIdx.x * 256 + threadIdx.x) * 8;
    f32x4 f0 = *(const f32x4*)(src + i);
    f32x4 f1 = *(const f32x4*)(src + i + 4);
    bf16x8 o;
    #pragma unroll
    for (int j = 0; j < 4; ++j) { o[j] = (bf16)f0[j]; o[4+j] = (bf16)f1[j]; }
    *(bf16x8*)(dst + i) = o;
}

// ---------------------------------------------------------------------------
// GEMM: C[m][n] = sum_k A[m][k] * B[n][k]   (A,B bf16 row-major, B^T input)
// m97 pattern: 128x128 tile, BK=32, 4 waves 2x2.
// MODE 0: C bf16 row-major.  MODE 1: C fp32.  MODE 2: C^T into vt layout.
// MODE 3: merged K/V projection — B is [wk; wv] (2048 rows); cols <1024 go to
//   Cv (kbuf, row-major, stride KVDIM); cols >=1024 go transposed into Cv2
//   (vtb [b][dcol][s]).  512 blocks = 2/CU so the vmcnt(0)+barrier drain
//   overlaps across blocks (m114).
// ---------------------------------------------------------------------------
template<int MODE>
__global__ __launch_bounds__(256)
void gemm_bt(const bf16* __restrict__ A, const bf16* __restrict__ B,
             void* __restrict__ Cv, void* __restrict__ Cv2, int M, int N, int K)
{
    __shared__ bf16 sA[128*32];
    __shared__ bf16 sB[128*32];

    const int tid  = threadIdx.x;
    const int wave = tid >> 6;
    const int lane = tid & 63;
    const int l15  = lane & 15;
    const int quad = lane >> 4;
    const int m_blk = blockIdx.y * 128;
    const int n_blk = blockIdx.x * 128;
    const int wm = (wave >> 1) * 64;
    const int wn = (wave & 1) * 64;

    f32x4 acc[4][4] = {};

    const int rowInSeg = lane >> 2;        // 0..15
    const int colInSeg = (lane & 3) * 8;   // 0,8,16,24

    for (int k0 = 0; k0 < K; k0 += 32) {
        __syncthreads();   // previous iteration's readers done
        #pragma unroll
        for (int i = 0; i < 2; ++i) {
            int s = wave * 2 + i;          // 8 segments of 16 rows each
            const bf16* ga = A + (size_t)(m_blk + s*16 + rowInSeg) * K + k0 + colInSeg;
            gl_lds16(ga, sA + s*512);
            const bf16* gb = B + (size_t)(n_blk + s*16 + rowInSeg) * K + k0 + colInSeg;
            gl_lds16(gb, sB + s*512);
        }
        __syncthreads();   // drains vmcnt(0) before barrier -> data landed

        bf16x8 af[4], bfr[4];
        #pragma unroll
        for (int mi = 0; mi < 4; ++mi)
            af[mi] = *(const bf16x8*)(sA + (wm + mi*16 + l15)*32 + quad*8);
        #pragma unroll
        for (int ni = 0; ni < 4; ++ni)
            bfr[ni] = *(const bf16x8*)(sB + (wn + ni*16 + l15)*32 + quad*8);
        #pragma unroll
        for (int mi = 0; mi < 4; ++mi)
            #pragma unroll
            for (int ni = 0; ni < 4; ++ni)
                acc[mi][ni] = __builtin_amdgcn_mfma_f32_16x16x32_bf16(
                                  af[mi], bfr[ni], acc[mi][ni], 0, 0, 0);
    }

    #pragma unroll
    for (int mi = 0; mi < 4; ++mi) {
        #pragma unroll
        for (int ni = 0; ni < 4; ++ni) {
            const int col = n_blk + wn + ni*16 + l15;
            const int row0 = m_blk + wm + mi*16 + quad*4;
            if constexpr (MODE == 2) {
                const int bb = row0 >> 11;          // /SEQ
                const int ss = row0 & (SEQ - 1);
                bf16x4 pk;
                #pragma unroll
                for (int r = 0; r < 4; ++r) pk[r] = (bf16)acc[mi][ni][r];
                *(bf16x4*)((bf16*)Cv + ((size_t)bb * KVDIM + col) * SEQ + ss) = pk;
            } else if constexpr (MODE == 1) {
                #pragma unroll
                for (int r = 0; r < 4; ++r)
                    ((float*)Cv)[(size_t)(row0 + r) * N + col] = acc[mi][ni][r];
            } else if constexpr (MODE == 3) {
                if (n_blk < KVDIM) {
                    // K path: row-major bf16, stride KVDIM
                    #pragma unroll
                    for (int r = 0; r < 4; ++r)
                        ((bf16*)Cv)[(size_t)(row0 + r) * KVDIM + col] = (bf16)acc[mi][ni][r];
                } else {
                    // V path: transposed into vt layout [b][dcol][s]
                    const int vcol = col - KVDIM;
                    const int bb = row0 >> 11;
                    const int ss = row0 & (SEQ - 1);
                    bf16x4 pk;
                    #pragma unroll
                    for (int r = 0; r < 4; ++r) pk[r] = (bf16)acc[mi][ni][r];
                    *(bf16x4*)((bf16*)Cv2 + ((size_t)bb * KVDIM + vcol) * SEQ + ss) = pk;
                }
            } else {
                #pragma unroll
                for (int r = 0; r < 4; ++r)
                    ((bf16*)Cv)[(size_t)(row0 + r) * N + col] = (bf16)acc[mi][ni][r];
            }
        }
    }
}

// ---------------------------------------------------------------------------
// 256x256 8-phase pipelined GEMM (m201 template port, plain HIP).
// r7: REVERTED to the r5 schedule (r6's hand-pipelined ds_reads regressed
// 130->213 us — m141-type failure: sched_barrier pinning + extra fragment set
// defeated the compiler's own overlap; r5's reads-before-barrier already hide
// under the barrier wait).  Added T1 XCD-chunked block remap: FETCH_SIZE was
// 153MB vs 64MB ideal — default round-robin scatters each XCD's blocks over
// all 16 grid rows (16 A-panels = 32MB >> 4MB L2); chunked gives each XCD 2
// rows -> 2 A-panels = 4MB ~ L2-resident.  Bijective (256 % 8 == 0).
// ---------------------------------------------------------------------------
#define LDB(p, qn, bf) { const char* base_ = (const char*)sB[p]; \
    _Pragma("unroll") for (int ni = 0; ni < 2; ++ni) \
    _Pragma("unroll") for (int ks = 0; ks < 2; ++ks) \
        bf[ni][ks] = *(const bf16x8*)(base_ + (wn + (qn)*32 + ni*16 + l15)*128 \
                                      + ((ks*64 + quad*16) ^ kx)); }

#define LDA(p, qm) { const char* base_ = (const char*)sA[p]; \
    _Pragma("unroll") for (int mi = 0; mi < 4; ++mi) \
    _Pragma("unroll") for (int ks = 0; ks < 2; ++ks) \
        af[mi][ks] = *(const bf16x8*)(base_ + (wm + (qm)*64 + mi*16 + l15)*128 \
                                      + ((ks*64 + quad*16) ^ kx)); }

#define MM(qm, qn, bf) { \
    _Pragma("unroll") for (int mi = 0; mi < 4; ++mi) \
    _Pragma("unroll") for (int ni = 0; ni < 2; ++ni) \
    _Pragma("unroll") for (int ks = 0; ks < 2; ++ks) \
        acc[(qm)*4+mi][(qn)*2+ni] = __builtin_amdgcn_mfma_f32_16x16x32_bf16( \
            af[mi][ks], bf[ni][ks], acc[(qm)*4+mi][(qn)*2+ni], 0, 0, 0); }

#define MIDBAR() { __builtin_amdgcn_s_barrier(); \
    asm volatile("s_waitcnt lgkmcnt(0)" ::: "memory"); \
    __builtin_amdgcn_sched_barrier(0); \
    __builtin_amdgcn_s_setprio(1); }

#define ENDBAR() { __builtin_amdgcn_s_setprio(0); \
    __builtin_amdgcn_sched_barrier(0); \
    __builtin_amdgcn_s_barrier(); }

#define ENDBAR_VM(n) { __builtin_amdgcn_s_setprio(0); \
    __builtin_amdgcn_sched_barrier(0); \
    asm volatile("s_waitcnt vmcnt(" #n ")" ::: "memory"); \
    __builtin_amdgcn_s_barrier(); }

template<bool F32OUT>
__global__ __launch_bounds__(512)
void gemm256(const bf16* __restrict__ A, const bf16* __restrict__ B,
             void* __restrict__ Cv, int M, int N, int K)
{
    __shared__ bf16 sA[2][256*64];   // 64 KB
    __shared__ bf16 sB[2][256*64];   // 64 KB

    const int tid  = threadIdx.x;
    const int wave = tid >> 6;
    const int lane = tid & 63;
    const int l15  = lane & 15;
    const int quad = lane >> 4;

    // T1: XCD-chunked remap. Block lin lands on XCD lin%8; give XCD j the
    // contiguous work chunk j*32..j*32+31 (2 grid rows -> A-panels L2-fit).
    const int lin = blockIdx.y * gridDim.x + blockIdx.x;
    const int cpx = (gridDim.x * gridDim.y) >> 3;      // 32
    const int swz = (lin & 7) * cpx + (lin >> 3);
    const int m_blk = (swz / gridDim.x) * 256;
    const int n_blk = (swz % gridDim.x) * 256;

    const int wm = (wave >> 2) * 128;     // wave M offset (0/128)
    const int wn = (wave & 3) * 64;       // wave N offset (0/64/128/192)
    const int kx = (l15 & 7) << 4;        // read-side swizzle XOR (row&7)<<4

    const bf16* Ag = A + (size_t)m_blk * K;
    const bf16* Bg = B + (size_t)n_blk * K;

    // staging lane geometry: 8-lane groups cover one 128B row, cols permuted
    // by the swizzle involution (slot_g = slot_lds ^ (row&7)).
    const int rs  = lane >> 3;                     // row within 8-row group
    const int sg8 = ((lane & 7) ^ rs) * 8;         // pre-swizzled col (elems)

    f32x4 acc[8][4] = {};

    // stage A interleaved-half h of buffer p at k0 (2 x global_load_lds)
    auto stA = [&](int p, int h, int k0) {
        bf16* sb = sA[p];
        const int r0 = h*64 + wave*8;              // rows r0..r0+7
        const int r1 = r0 + 128;                   // rows r1..r1+7
        gl_lds16(Ag + (size_t)(r0 + rs)*K + k0 + sg8, sb + r0*64);
        gl_lds16(Ag + (size_t)(r1 + rs)*K + k0 + sg8, sb + r1*64);
    };
    // stage B qn-half h of buffer p at k0 (2 x global_load_lds)
    auto stB = [&](int p, int h, int k0) {
        bf16* sb = sB[p];
        #pragma unroll
        for (int j = 0; j < 2; ++j) {
            const int s  = j*8 + wave;             // segment 0..15
            const int rb = (s>>2)*64 + h*32 + (s&3)*8;
            gl_lds16(Bg + (size_t)(rb + rs)*K + k0 + sg8, sb + rb*64);
        }
    };

    bf16x8 af[4][2], b0[2][2], b1[2][2];

    // ---- prologue: tile0 all 4 halves, then tile1 {A-ih0, B-qn0, B-qn1}
    stA(0, 0, 0);  stA(0, 1, 0);  stB(0, 0, 0);  stB(0, 1, 0);
    stA(1, 0, 64); stB(1, 0, 64); stB(1, 1, 64);
    asm volatile("s_waitcnt vmcnt(6)" ::: "memory");   // tile0 landed
    __builtin_amdgcn_s_barrier();

    const int niter = K >> 7;                      // K/128 (2 K-tiles/iter)
    for (int it = 0; it < niter; ++it) {
        const int kc  = it << 7;
        const bool pre = (it + 1 < niter);

        // ================= K-tile 2it (buf 0) =================
        // P1: read A-ih0 + B-qn0; stage buf1.A-ih1 (tile 2it+1)
        LDA(0, 0); LDB(0, 0, b0);
        stA(1, 1, kc + 64);
        MIDBAR(); MM(0, 0, b0); ENDBAR();

        // P2: read B-qn1; stage buf0.A-ih0 (tile 2it+2)
        LDB(0, 1, b1);
        if (pre) stA(0, 0, kc + 128);
        MIDBAR(); MM(0, 1, b1); ENDBAR();

        // P3: read A-ih1; stage buf0.B-qn0
        LDA(0, 1);
        if (pre) stB(0, 0, kc + 128);
        MIDBAR(); MM(1, 0, b0); ENDBAR();

        // P4: stage buf0.B-qn1; counted vmcnt
        if (pre) stB(0, 1, kc + 128);
        MIDBAR(); MM(1, 1, b1);
        if (pre) { ENDBAR_VM(6); } else { ENDBAR_VM(0); }

        // ================= K-tile 2it+1 (buf 1) =================
        // P5: read A-ih0 + B-qn0; stage buf0.A-ih1
        LDA(1, 0); LDB(1, 0, b0);
        if (pre) stA(0, 1, kc + 128);
        MIDBAR(); MM(0, 0, b0); ENDBAR();

        // P6: read B-qn1; stage buf1.A-ih0 (tile 2it+3)
        LDB(1, 1, b1);
        if (pre) stA(1, 0, kc + 192);
        MIDBAR(); MM(0, 1, b1); ENDBAR();

        // P7: read A-ih1; stage buf1.B-qn0
        LDA(1, 1);
        if (pre) stB(1, 0, kc + 192);
        MIDBAR(); MM(1, 0, b0); ENDBAR();

        // P8: stage buf1.B-qn1; counted vmcnt
        if (pre) stB(1, 1, kc + 192);
        MIDBAR(); MM(1, 1, b1);
        if (pre) { ENDBAR_VM(6); } else { ENDBAR(); }
    }

    // ---- epilogue: acc[qm*4+mi][qn*2+ni] -> C
    #pragma unroll
    for (int ai = 0; ai < 8; ++ai) {
        const int row0 = m_blk + wm + (ai>>2)*64 + (ai&3)*16 + quad*4;
        #pragma unroll
        for (int bi = 0; bi < 4; ++bi) {
            const int col = n_blk + wn + (bi>>1)*32 + (bi&1)*16 + l15;
            if constexpr (F32OUT) {
                #pragma unroll
                for (int r = 0; r < 4; ++r)
                    ((float*)Cv)[(size_t)(row0 + r)*N + col] = acc[ai][bi][r];
            } else {
                #pragma unroll
                for (int r = 0; r < 4; ++r)
                    ((bf16*)Cv)[(size_t)(row0 + r)*N + col] = (bf16)acc[ai][bi][r];
            }
        }
    }
}

// ---------------------------------------------------------------------------
// Per-head LayerNorm + RoPE, in place on bf16 workspace. One wave per
// (token, head); lane j holds dims j and j+64 (the RoPE pair). w is fp32.
// ---------------------------------------------------------------------------
__global__ __launch_bounds__(256)
void ln_rope(bf16* __restrict__ buf, const float* __restrict__ w,
             const int* __restrict__ pos, int nh)
{
    const int id   = blockIdx.x * 4 + (threadIdx.x >> 6);
    const int lane = threadIdx.x & 63;
    const int t  = id / nh;
    const int hh = id - t * nh;

    bf16* p = buf + (size_t)t * nh * HD + hh * HD;
    float x1 = (float)p[lane];
    float x2 = (float)p[lane + 64];

    float s1 = x1 + x2, s2 = x1*x1 + x2*x2;
    #pragma unroll
    for (int m = 1; m < 64; m <<= 1) {
        s1 += __shfl_xor(s1, m);
        s2 += __shfl_xor(s2, m);
    }
    const float mean = s1 * (1.0f/128.0f);
    const float var  = s2 * (1.0f/128.0f) - mean*mean;
    const float rs   = rsqrtf(fmaxf(var, 0.0f) + 1e-5f);

    const float w1 = w[hh*HD + lane];
    const float w2 = w[hh*HD + lane + 64];
    const float xn1 = (x1 - mean) * rs * w1;
    const float xn2 = (x2 - mean) * rs * w2;

    const int s = t & (SEQ - 1);
    // inv_freq = 10000^(-lane/64) = exp(-lane * ln(10000)/64)
    const float ang = (float)pos[s] * __expf(-(float)lane * (9.210340371976184f/64.0f));
    const float c = cosf(ang), sn = sinf(ang);

    p[lane]      = (bf16)(xn1 * c - xn2 * sn);
    p[lane + 64] = (bf16)(xn2 * c + xn1 * sn);
}

// ---------------------------------------------------------------------------
// Flash attention, causal, GQA — 8-wave swapped-operand structure (m214 port)
//   block = 256 q rows (8 waves x 32), KV tile = 64, mfma_f32_32x32x16_bf16
//   QK^T computed as mfma(K,Q)  -> S^T : q on lane&31, kv on regs
//   PV   computed as mfma(Vt,P) -> O^T : q on lane&31, d  on regs
//   => softmax max/sum, O-rescale, l-division all lane-local; P never
//      touches LDS (cross-half exchange via shfl_xor(.,32), T12)
//   K and V^T staged to XOR-swizzled LDS (T2), double-buffered, reg-staged
//   issue-early/write-late (T14), one barrier per tile, setprio on MFMA (T5),
//   defer-max THR=8 in log2 domain (T13).
//   Causal balance: qt mirrored on batch so every CU's 2 resident blocks sum
//   to the same kv work (36 tile-units) — kills the 1.8x makespan tail.
//   NOTE: permlane32_swap attempt (r3) FAILED correctness — swap-direction
//   semantics unverified; exchange uses harness-verified shfl_xor form.
// ---------------------------------------------------------------------------
struct StReg { bf16x8 k0, k1, v0, v1; };

__device__ __forceinline__ StReg stage_load(const bf16* kgp, const bf16* vgp, int t)
{
    StReg r;
    const size_t ko = (size_t)t * 64 * KVDIM;
    r.k0 = *(const bf16x8*)(kgp + ko);
    r.k1 = *(const bf16x8*)(kgp + ko + 64);
    r.v0 = *(const bf16x8*)(vgp + t*64);
    r.v1 = *(const bf16x8*)(vgp + t*64 + 32);
    return r;
}

__device__ __forceinline__ void stage_write(bf16* dk, bf16* dv, const StReg& r,
                                            int krow, int kcb, int vrow, int vcb)
{
    // K: [64 rows][128 cols] bf16, row stride 256B, byte ^= (row&7)<<4
    *(bf16x8*)((char*)dk + krow*256 + ( kcb        ^ ((krow&7)<<4))) = r.k0;
    *(bf16x8*)((char*)dk + krow*256 + ((kcb + 128) ^ ((krow&7)<<4))) = r.k1;
    // V^T: [128 d][64 kv] bf16, row stride 128B, same involution
    *(bf16x8*)((char*)dv + vrow*128 + ( vcb        ^ ((vrow&7)<<4))) = r.v0;
    *(bf16x8*)((char*)dv + vrow*128 + ((vcb +  64) ^ ((vrow&7)<<4))) = r.v1;
}

__device__ __forceinline__ unsigned pk2(float x, float y)
{
    union { bf16 h[2]; unsigned u; } c;
    c.h[0] = (bf16)x; c.h[1] = (bf16)y;
    return c.u;
}

__global__ __launch_bounds__(512, 2)
void attn_fa(bf16* __restrict__ qob,        // [NTOK][QDIM], Q in / O out
             const bf16* __restrict__ kbp,  // [NTOK][KVDIM]
             const bf16* __restrict__ vtb)  // [B][KVDIM][SEQ]  (V transposed)
{
    __shared__ bf16 sK[2][64*128];   // 32 KB, swizzled
    __shared__ bf16 sV[2][128*64];   // 32 KB, swizzled

    const int tid  = threadIdx.x;
    const int wave = tid >> 6;
    const int lane = tid & 63;
    const int l31  = lane & 31;
    const int hi   = lane >> 5;

    const int b  = blockIdx.z;       // batch (2)
    // mirror qt on batch: co-resident block pair (x,b=0)+(x,b=1) has constant
    // total kv work -> balanced per-CU makespan under round-robin dispatch
    const int qt = b ? (gridDim.x - 1 - blockIdx.x) : blockIdx.x;
    const int h  = blockIdx.y;       // q head (32)
    const int hk = h >> 2;
    const int qbase = qt * 256;
    const int qw    = qbase + wave * 32;   // wave's first q row
    const int qrow  = qw + l31;            // this lane's q row

    // ---- Q fragments (B operand): lane holds Q[qrow][ks*16 + hi*8 + 0..7]
    bf16x8 qf[8];
    {
        const bf16* qp = qob + (size_t)(b*SEQ + qrow)*QDIM + h*HD + hi*8;
        #pragma unroll
        for (int ks = 0; ks < 8; ++ks)
            qf[ks] = *(const bf16x8*)(qp + ks*16);
    }

    f32x16 oacc[4] = {};             // O^T: q = lane&31, d = dblk*32 + crow(reg,hi)
    float m_i = NEGBIG, l_i = 0.0f;

    // staging geometry (512 threads, 2 x 16B per tile for each of K, V^T)
    const int krow = tid >> 3;             // 0..63
    const int kcb  = (tid & 7) * 16;       // byte col 0..112
    const int vrow = tid >> 2;             // 0..127
    const int vcb  = (tid & 3) * 16;       // byte col 0..48
    const bf16* kgp = kbp + (size_t)(b*SEQ + krow)*KVDIM + hk*HD + (tid & 7)*8;
    const bf16* vgp = vtb + ((size_t)(b*NKV + hk)*HD + vrow)*SEQ + (tid & 3)*8;

    const int ntiles = qt*4 + 4;
    const float SC = 0.08838834764831845f * 1.4426950408889634f;  // scale*log2e
    const int kx = (l31 & 7) << 4;         // read-side swizzle (rows ≡ l31 mod 8)

    // prologue: stage tile 0 into buffer 0
    {
        StReg r = stage_load(kgp, vgp, 0);
        stage_write(sK[0], sV[0], r, krow, kcb, vrow, vcb);
    }
    __syncthreads();

    int cur = 0;
    for (int t = 0; t < ntiles; ++t) {
        const int kv0 = t * 64;
        const bool hn = (t + 1 < ntiles);
        StReg nx;
        if (hn) nx = stage_load(kgp, vgp, t + 1);   // issue early (T14)

        if (kv0 <= qw + 31) {                       // skip fully-masked tiles
            // ---- S^T = K·Q^T : 16 mfma, kv on regs, q on lanes
            f32x16 sa0 = {}, sa1 = {};
            const char* kl = (const char*)sK[cur];
            __builtin_amdgcn_s_setprio(1);
            #pragma unroll
            for (int ks = 0; ks < 8; ++ks) {
                const int cb = ks*32 + hi*16;
                bf16x8 k0 = *(const bf16x8*)(kl + l31*256        + (cb ^ kx));
                bf16x8 k1 = *(const bf16x8*)(kl + l31*256 + 8192 + (cb ^ kx));
                sa0 = __builtin_amdgcn_mfma_f32_32x32x16_bf16(k0, qf[ks], sa0, 0, 0, 0);
                sa1 = __builtin_amdgcn_mfma_f32_32x32x16_bf16(k1, qf[ks], sa1, 0, 0, 0);
            }
            __builtin_amdgcn_s_setprio(0);

            // ---- scale (log2 domain) + causal mask on diagonal tiles
            float s[32];
            #pragma unroll
            for (int r = 0; r < 16; ++r) { s[r] = sa0[r]*SC; s[16+r] = sa1[r]*SC; }
            if (kv0 + 63 > qw) {
                #pragma unroll
                for (int j = 0; j < 32; ++j) {
                    const int kv = kv0 + (j>>4)*32 + (j&3) + ((j>>2)&3)*8 + hi*4;
                    if (kv > qrow) s[j] = NEGBIG;
                }
            }

            // ---- online softmax, lane-local (partner lane = other 32 kv)
            float mt = s[0];
            #pragma unroll
            for (int j = 1; j < 32; ++j) mt = fmaxf(mt, s[j]);
            mt = fmaxf(mt, __shfl_xor(mt, 32));
            if (__any(mt > m_i + 8.0f)) {           // defer-max (T13)
                const float mnew = fmaxf(m_i, mt);
                const float al = exp2f(m_i - mnew);
                m_i = mnew; l_i *= al;
                #pragma unroll
                for (int d = 0; d < 4; ++d)
                    #pragma unroll
                    for (int r = 0; r < 16; ++r) oacc[d][r] *= al;
            }
            float p[32]; float sum = 0.0f;
            #pragma unroll
            for (int j = 0; j < 32; ++j) { p[j] = exp2f(s[j] - m_i); sum += p[j]; }
            sum += __shfl_xor(sum, 32);
            l_i += sum;

            // ---- P -> bf16 B-fragments, cross-half exchange (T12 w/ shfl)
            // pb[ks][j] = P[q][ks*16 + hi*8 + j]; src idx base c = (ks>>1)*16+(ks&1)*8
            bf16x8 pb[4];
            #pragma unroll
            for (int ks = 0; ks < 4; ++ks) {
                const int c = (ks>>1)*16 + (ks&1)*8;
                const unsigned a0 = pk2(p[c+0], p[c+1]);
                const unsigned a1 = pk2(p[c+2], p[c+3]);
                const unsigned b0 = pk2(p[c+4], p[c+5]);
                const unsigned b1 = pk2(p[c+6], p[c+7]);
                const unsigned r0 = (unsigned)__shfl_xor((int)(hi ? a0 : b0), 32);
                const unsigned r1 = (unsigned)__shfl_xor((int)(hi ? a1 : b1), 32);
                union { unsigned u[4]; bf16x8 v; } fr;
                fr.u[0] = hi ? r0 : a0;
                fr.u[1] = hi ? r1 : a1;
                fr.u[2] = hi ? b0 : r0;
                fr.u[3] = hi ? b1 : r1;
                pb[ks] = fr.v;
            }

            // ---- O^T += V^T·P : 16 mfma, d on regs, q on lanes
            const char* vl = (const char*)sV[cur];
            __builtin_amdgcn_s_setprio(1);
            #pragma unroll
            for (int d = 0; d < 4; ++d) {
                #pragma unroll
                for (int ks = 0; ks < 4; ++ks) {
                    const int cb = ks*32 + hi*16;
                    bf16x8 vf = *(const bf16x8*)(vl + (d*32 + l31)*128 + (cb ^ kx));
                    oacc[d] = __builtin_amdgcn_mfma_f32_32x32x16_bf16(vf, pb[ks], oacc[d], 0, 0, 0);
                }
            }
            __builtin_amdgcn_s_setprio(0);
        }

        if (hn) stage_write(sK[cur^1], sV[cur^1], nx, krow, kcb, vrow, vcb);
        __syncthreads();
        cur ^= 1;
    }

    // ---- epilogue: O/l back into qob (q = lane&31 -> lane-local l)
    const float inv = 1.0f / l_i;
    bf16* op = qob + (size_t)(b*SEQ + qrow)*QDIM + h*HD + hi*4;
    #pragma unroll
    for (int d = 0; d < 4; ++d) {
        #pragma unroll
        for (int q2 = 0; q2 < 4; ++q2) {
            bf16x4 pk;
            #pragma unroll
            for (int r = 0; r < 4; ++r) pk[r] = (bf16)(oacc[d][q2*4 + r] * inv);
            *(bf16x4*)(op + d*32 + q2*8) = pk;   // d = d*32 + q2*8 + hi*4 + r
        }
    }
}

// ---------------------------------------------------------------------------
extern "C" void kernel_launch(void* const* d_in, const int* in_sizes, int n_in,
                              void* d_out, int out_size, void* d_ws, size_t ws_size,
                              hipStream_t stream)
{
    // fp32 inputs per the reference dtypes
    const float* hidden = (const float*)d_in[0];
    const int*   pos    = (const int*)d_in[1];
    const float* wq     = (const float*)d_in[2];
    const float* wk     = (const float*)d_in[3];
    const float* wv     = (const float*)d_in[4];
    const float* wo     = (const float*)d_in[5];
    const float* qw     = (const float*)d_in[6];
    const float* kw     = (const float*)d_in[7];

    // bf16 workspace, 128 MB total (wo reuses the dead wq slot)
    bf16* hb   = (bf16*)d_ws;                          // [NTOK][HIDDEN]  32MB
    bf16* wqb  = hb   + (size_t)NTOK*HIDDEN;           // [QDIM][HIDDEN]  32MB (wq, then wo)
    bf16* wkb  = wqb  + (size_t)QDIM*HIDDEN;           // [KVDIM][HIDDEN]  8MB
    bf16* wvb  = wkb  + (size_t)KVDIM*HIDDEN;          // [KVDIM][HIDDEN]  8MB (contiguous after wkb!)
    bf16* qbuf = wvb  + (size_t)KVDIM*HIDDEN;          // [NTOK][QDIM]    32MB (Q, then attn out)
    bf16* kbuf = qbuf + (size_t)NTOK*QDIM;             // [NTOK][KVDIM]    8MB
    bf16* vtb  = kbuf + (size_t)NTOK*KVDIM;            // [B][KVDIM][SEQ]  8MB
    float* out = (float*)d_out;                        // fp32 output

    const dim3 blk(256);

    // fp32 -> bf16 pre-conversion (each size divisible by 2048)
    cvt_f32_bf16<<<dim3(NTOK*HIDDEN/2048),  blk, 0, stream>>>(hidden, hb);
    cvt_f32_bf16<<<dim3(QDIM*HIDDEN/2048),  blk, 0, stream>>>(wq, wqb);
    cvt_f32_bf16<<<dim3(KVDIM*HIDDEN/2048), blk, 0, stream>>>(wk, wkb);
    cvt_f32_bf16<<<dim3(KVDIM*HIDDEN/2048), blk, 0, stream>>>(wv, wvb);

    // Q-proj: 4096x4096x4096 -> 8-phase 256^2 kernel (grid 16x16 = 256 blocks)
    gemm256<false><<<dim3(QDIM/256, NTOK/256), dim3(512), 0, stream>>>(hb, wqb, qbuf, NTOK, QDIM, HIDDEN);

    // K+V proj merged: B = [wk; wv] (contiguous, 2048 rows), grid 16x32 = 512
    // blocks = 2 blocks/CU. Epilogue splits: cols<1024 -> kbuf, else vtb^T.
    gemm_bt<3><<<dim3((2*KVDIM)/128, NTOK/128), blk, 0, stream>>>(hb, wkb, kbuf, vtb, NTOK, 2*KVDIM, HIDDEN);

    // wq slot is dead after the Q-GEMM; stream order makes this safe
    cvt_f32_bf16<<<dim3(QDIM*HIDDEN/2048), blk, 0, stream>>>(wo, wqb);

    ln_rope<<<dim3(NTOK*NH/4),  blk, 0, stream>>>(qbuf, qw, pos, NH);
    ln_rope<<<dim3(NTOK*NKV/4), blk, 0, stream>>>(kbuf, kw, pos, NKV);

    attn_fa<<<dim3(SEQ/256, NH, BATCH), dim3(512), 0, stream>>>(qbuf, kbuf, vtb);

    // out-proj: 4096x4096x4096, fp32 out -> 8-phase kernel
    gemm256<true><<<dim3(QDIM/256, NTOK/256), dim3(512), 0, stream>>>(qbuf, wqb, out, NTOK, QDIM, HIDDEN);
}

// Round 8
// 714.816 us; speedup vs baseline: 1.2401x; 1.0039x over previous
//
#include <hip/hip_runtime.h>
#include <hip/hip_bf16.h>
#include <stdint.h>
#include <math.h>

typedef __bf16 bf16;
typedef __bf16 bf16x4 __attribute__((ext_vector_type(4)));
typedef __bf16 bf16x8 __attribute__((ext_vector_type(8)));
typedef float  f32x4  __attribute__((ext_vector_type(4)));
typedef float  f32x16 __attribute__((ext_vector_type(16)));

#define HIDDEN 4096
#define NH     32
#define NKV    8
#define HD     128
#define SEQ    2048
#define BATCH  2
#define NTOK   (BATCH*SEQ)   // 4096
#define QDIM   (NH*HD)       // 4096
#define KVDIM  (NKV*HD)      // 1024

#define NEGBIG (-3.0e38f)

__device__ __forceinline__ void gl_lds16(const bf16* g, bf16* l) {
    // async global->LDS, 16B/lane; LDS dest is wave-uniform base + lane*16
    __builtin_amdgcn_global_load_lds((__attribute__((address_space(1))) void*)g,
                                     (__attribute__((address_space(3))) void*)l,
                                     16, 0, 0);
}

// ---------------------------------------------------------------------------
// fp32 -> bf16 bulk convert, 8 elem/thread (two f32x4 loads, one 16B store)
// ---------------------------------------------------------------------------
__device__ __forceinline__ void cvt_body(const float* __restrict__ src,
                                         bf16* __restrict__ dst, int blk, int tid)
{
    const size_t i = ((size_t)blk * 256 + tid) * 8;
    f32x4 f0 = *(const f32x4*)(src + i);
    f32x4 f1 = *(const f32x4*)(src + i + 4);
    bf16x8 o;
    #pragma unroll
    for (int j = 0; j < 4; ++j) { o[j] = (bf16)f0[j]; o[4+j] = (bf16)f1[j]; }
    *(bf16x8*)(dst + i) = o;
}

__global__ __launch_bounds__(256)
void cvt_f32_bf16(const float* __restrict__ src, bf16* __restrict__ dst)
{
    cvt_body(src, dst, blockIdx.x, threadIdx.x);
}

// Fused 4-region convert (hidden, wq, wk, wv) — one launch instead of four.
// Region boundaries in 2048-elem blocks: 8192 / 8192 / 2048 / 2048 = 20480.
__global__ __launch_bounds__(256)
void cvt4(const float* __restrict__ s0, bf16* __restrict__ d0,
          const float* __restrict__ s1, bf16* __restrict__ d1,
          const float* __restrict__ s2, bf16* __restrict__ d2,
          const float* __restrict__ s3, bf16* __restrict__ d3)
{
    const int b = blockIdx.x;
    if      (b < 8192)  cvt_body(s0, d0, b,         threadIdx.x);
    else if (b < 16384) cvt_body(s1, d1, b - 8192,  threadIdx.x);
    else if (b < 18432) cvt_body(s2, d2, b - 16384, threadIdx.x);
    else                cvt_body(s3, d3, b - 18432, threadIdx.x);
}

// ---------------------------------------------------------------------------
// GEMM: C[m][n] = sum_k A[m][k] * B[n][k]   (A,B bf16 row-major, B^T input)
// m97 pattern: 128x128 tile, BK=32, 4 waves 2x2.
// MODE 0: C bf16 row-major.  MODE 1: C fp32.  MODE 2: C^T into vt layout.
// MODE 3: merged K/V projection — B is [wk; wv] (2048 rows); cols <1024 go to
//   Cv (kbuf, row-major, stride KVDIM); cols >=1024 go transposed into Cv2
//   (vtb [b][dcol][s]).  512 blocks = 2/CU so the vmcnt(0)+barrier drain
//   overlaps across blocks (m114).
// ---------------------------------------------------------------------------
template<int MODE>
__global__ __launch_bounds__(256)
void gemm_bt(const bf16* __restrict__ A, const bf16* __restrict__ B,
             void* __restrict__ Cv, void* __restrict__ Cv2, int M, int N, int K)
{
    __shared__ bf16 sA[128*32];
    __shared__ bf16 sB[128*32];

    const int tid  = threadIdx.x;
    const int wave = tid >> 6;
    const int lane = tid & 63;
    const int l15  = lane & 15;
    const int quad = lane >> 4;
    const int m_blk = blockIdx.y * 128;
    const int n_blk = blockIdx.x * 128;
    const int wm = (wave >> 1) * 64;
    const int wn = (wave & 1) * 64;

    f32x4 acc[4][4] = {};

    const int rowInSeg = lane >> 2;        // 0..15
    const int colInSeg = (lane & 3) * 8;   // 0,8,16,24

    for (int k0 = 0; k0 < K; k0 += 32) {
        __syncthreads();   // previous iteration's readers done
        #pragma unroll
        for (int i = 0; i < 2; ++i) {
            int s = wave * 2 + i;          // 8 segments of 16 rows each
            const bf16* ga = A + (size_t)(m_blk + s*16 + rowInSeg) * K + k0 + colInSeg;
            gl_lds16(ga, sA + s*512);
            const bf16* gb = B + (size_t)(n_blk + s*16 + rowInSeg) * K + k0 + colInSeg;
            gl_lds16(gb, sB + s*512);
        }
        __syncthreads();   // drains vmcnt(0) before barrier -> data landed

        bf16x8 af[4], bfr[4];
        #pragma unroll
        for (int mi = 0; mi < 4; ++mi)
            af[mi] = *(const bf16x8*)(sA + (wm + mi*16 + l15)*32 + quad*8);
        #pragma unroll
        for (int ni = 0; ni < 4; ++ni)
            bfr[ni] = *(const bf16x8*)(sB + (wn + ni*16 + l15)*32 + quad*8);
        #pragma unroll
        for (int mi = 0; mi < 4; ++mi)
            #pragma unroll
            for (int ni = 0; ni < 4; ++ni)
                acc[mi][ni] = __builtin_amdgcn_mfma_f32_16x16x32_bf16(
                                  af[mi], bfr[ni], acc[mi][ni], 0, 0, 0);
    }

    #pragma unroll
    for (int mi = 0; mi < 4; ++mi) {
        #pragma unroll
        for (int ni = 0; ni < 4; ++ni) {
            const int col = n_blk + wn + ni*16 + l15;
            const int row0 = m_blk + wm + mi*16 + quad*4;
            if constexpr (MODE == 2) {
                const int bb = row0 >> 11;          // /SEQ
                const int ss = row0 & (SEQ - 1);
                bf16x4 pk;
                #pragma unroll
                for (int r = 0; r < 4; ++r) pk[r] = (bf16)acc[mi][ni][r];
                *(bf16x4*)((bf16*)Cv + ((size_t)bb * KVDIM + col) * SEQ + ss) = pk;
            } else if constexpr (MODE == 1) {
                #pragma unroll
                for (int r = 0; r < 4; ++r)
                    ((float*)Cv)[(size_t)(row0 + r) * N + col] = acc[mi][ni][r];
            } else if constexpr (MODE == 3) {
                if (n_blk < KVDIM) {
                    // K path: row-major bf16, stride KVDIM
                    #pragma unroll
                    for (int r = 0; r < 4; ++r)
                        ((bf16*)Cv)[(size_t)(row0 + r) * KVDIM + col] = (bf16)acc[mi][ni][r];
                } else {
                    // V path: transposed into vt layout [b][dcol][s]
                    const int vcol = col - KVDIM;
                    const int bb = row0 >> 11;
                    const int ss = row0 & (SEQ - 1);
                    bf16x4 pk;
                    #pragma unroll
                    for (int r = 0; r < 4; ++r) pk[r] = (bf16)acc[mi][ni][r];
                    *(bf16x4*)((bf16*)Cv2 + ((size_t)bb * KVDIM + vcol) * SEQ + ss) = pk;
                }
            } else {
                #pragma unroll
                for (int r = 0; r < 4; ++r)
                    ((bf16*)Cv)[(size_t)(row0 + r) * N + col] = (bf16)acc[mi][ni][r];
            }
        }
    }
}

// ---------------------------------------------------------------------------
// 256x256 8-phase pipelined GEMM (m201 template port, plain HIP).
// r7 schedule (r6's hand-pipelined ds_reads regressed — m141-type failure).
// T1 XCD-chunked block remap (bijective, 256 % 8 == 0).
// ---------------------------------------------------------------------------
#define LDB(p, qn, bf) { const char* base_ = (const char*)sB[p]; \
    _Pragma("unroll") for (int ni = 0; ni < 2; ++ni) \
    _Pragma("unroll") for (int ks = 0; ks < 2; ++ks) \
        bf[ni][ks] = *(const bf16x8*)(base_ + (wn + (qn)*32 + ni*16 + l15)*128 \
                                      + ((ks*64 + quad*16) ^ kx)); }

#define LDA(p, qm) { const char* base_ = (const char*)sA[p]; \
    _Pragma("unroll") for (int mi = 0; mi < 4; ++mi) \
    _Pragma("unroll") for (int ks = 0; ks < 2; ++ks) \
        af[mi][ks] = *(const bf16x8*)(base_ + (wm + (qm)*64 + mi*16 + l15)*128 \
                                      + ((ks*64 + quad*16) ^ kx)); }

#define MM(qm, qn, bf) { \
    _Pragma("unroll") for (int mi = 0; mi < 4; ++mi) \
    _Pragma("unroll") for (int ni = 0; ni < 2; ++ni) \
    _Pragma("unroll") for (int ks = 0; ks < 2; ++ks) \
        acc[(qm)*4+mi][(qn)*2+ni] = __builtin_amdgcn_mfma_f32_16x16x32_bf16( \
            af[mi][ks], bf[ni][ks], acc[(qm)*4+mi][(qn)*2+ni], 0, 0, 0); }

#define MIDBAR() { __builtin_amdgcn_s_barrier(); \
    asm volatile("s_waitcnt lgkmcnt(0)" ::: "memory"); \
    __builtin_amdgcn_sched_barrier(0); \
    __builtin_amdgcn_s_setprio(1); }

#define ENDBAR() { __builtin_amdgcn_s_setprio(0); \
    __builtin_amdgcn_sched_barrier(0); \
    __builtin_amdgcn_s_barrier(); }

#define ENDBAR_VM(n) { __builtin_amdgcn_s_setprio(0); \
    __builtin_amdgcn_sched_barrier(0); \
    asm volatile("s_waitcnt vmcnt(" #n ")" ::: "memory"); \
    __builtin_amdgcn_s_barrier(); }

template<bool F32OUT>
__global__ __launch_bounds__(512)
void gemm256(const bf16* __restrict__ A, const bf16* __restrict__ B,
             void* __restrict__ Cv, int M, int N, int K)
{
    __shared__ bf16 sA[2][256*64];   // 64 KB
    __shared__ bf16 sB[2][256*64];   // 64 KB

    const int tid  = threadIdx.x;
    const int wave = tid >> 6;
    const int lane = tid & 63;
    const int l15  = lane & 15;
    const int quad = lane >> 4;

    // T1: XCD-chunked remap. Block lin lands on XCD lin%8; give XCD j the
    // contiguous work chunk j*32..j*32+31 (2 grid rows -> A-panels L2-fit).
    const int lin = blockIdx.y * gridDim.x + blockIdx.x;
    const int cpx = (gridDim.x * gridDim.y) >> 3;      // 32
    const int swz = (lin & 7) * cpx + (lin >> 3);
    const int m_blk = (swz / gridDim.x) * 256;
    const int n_blk = (swz % gridDim.x) * 256;

    const int wm = (wave >> 2) * 128;     // wave M offset (0/128)
    const int wn = (wave & 3) * 64;       // wave N offset (0/64/128/192)
    const int kx = (l15 & 7) << 4;        // read-side swizzle XOR (row&7)<<4

    const bf16* Ag = A + (size_t)m_blk * K;
    const bf16* Bg = B + (size_t)n_blk * K;

    // staging lane geometry: 8-lane groups cover one 128B row, cols permuted
    // by the swizzle involution (slot_g = slot_lds ^ (row&7)).
    const int rs  = lane >> 3;                     // row within 8-row group
    const int sg8 = ((lane & 7) ^ rs) * 8;         // pre-swizzled col (elems)

    f32x4 acc[8][4] = {};

    // stage A interleaved-half h of buffer p at k0 (2 x global_load_lds)
    auto stA = [&](int p, int h, int k0) {
        bf16* sb = sA[p];
        const int r0 = h*64 + wave*8;              // rows r0..r0+7
        const int r1 = r0 + 128;                   // rows r1..r1+7
        gl_lds16(Ag + (size_t)(r0 + rs)*K + k0 + sg8, sb + r0*64);
        gl_lds16(Ag + (size_t)(r1 + rs)*K + k0 + sg8, sb + r1*64);
    };
    // stage B qn-half h of buffer p at k0 (2 x global_load_lds)
    auto stB = [&](int p, int h, int k0) {
        bf16* sb = sB[p];
        #pragma unroll
        for (int j = 0; j < 2; ++j) {
            const int s  = j*8 + wave;             // segment 0..15
            const int rb = (s>>2)*64 + h*32 + (s&3)*8;
            gl_lds16(Bg + (size_t)(rb + rs)*K + k0 + sg8, sb + rb*64);
        }
    };

    bf16x8 af[4][2], b0[2][2], b1[2][2];

    // ---- prologue: tile0 all 4 halves, then tile1 {A-ih0, B-qn0, B-qn1}
    stA(0, 0, 0);  stA(0, 1, 0);  stB(0, 0, 0);  stB(0, 1, 0);
    stA(1, 0, 64); stB(1, 0, 64); stB(1, 1, 64);
    asm volatile("s_waitcnt vmcnt(6)" ::: "memory");   // tile0 landed
    __builtin_amdgcn_s_barrier();

    const int niter = K >> 7;                      // K/128 (2 K-tiles/iter)
    for (int it = 0; it < niter; ++it) {
        const int kc  = it << 7;
        const bool pre = (it + 1 < niter);

        // ================= K-tile 2it (buf 0) =================
        // P1: read A-ih0 + B-qn0; stage buf1.A-ih1 (tile 2it+1)
        LDA(0, 0); LDB(0, 0, b0);
        stA(1, 1, kc + 64);
        MIDBAR(); MM(0, 0, b0); ENDBAR();

        // P2: read B-qn1; stage buf0.A-ih0 (tile 2it+2)
        LDB(0, 1, b1);
        if (pre) stA(0, 0, kc + 128);
        MIDBAR(); MM(0, 1, b1); ENDBAR();

        // P3: read A-ih1; stage buf0.B-qn0
        LDA(0, 1);
        if (pre) stB(0, 0, kc + 128);
        MIDBAR(); MM(1, 0, b0); ENDBAR();

        // P4: stage buf0.B-qn1; counted vmcnt
        if (pre) stB(0, 1, kc + 128);
        MIDBAR(); MM(1, 1, b1);
        if (pre) { ENDBAR_VM(6); } else { ENDBAR_VM(0); }

        // ================= K-tile 2it+1 (buf 1) =================
        // P5: read A-ih0 + B-qn0; stage buf0.A-ih1
        LDA(1, 0); LDB(1, 0, b0);
        if (pre) stA(0, 1, kc + 128);
        MIDBAR(); MM(0, 0, b0); ENDBAR();

        // P6: read B-qn1; stage buf1.A-ih0 (tile 2it+3)
        LDB(1, 1, b1);
        if (pre) stA(1, 0, kc + 192);
        MIDBAR(); MM(0, 1, b1); ENDBAR();

        // P7: read A-ih1; stage buf1.B-qn0
        LDA(1, 1);
        if (pre) stB(1, 0, kc + 192);
        MIDBAR(); MM(1, 0, b0); ENDBAR();

        // P8: stage buf1.B-qn1; counted vmcnt
        if (pre) stB(1, 1, kc + 192);
        MIDBAR(); MM(1, 1, b1);
        if (pre) { ENDBAR_VM(6); } else { ENDBAR(); }
    }

    // ---- epilogue: acc[qm*4+mi][qn*2+ni] -> C
    #pragma unroll
    for (int ai = 0; ai < 8; ++ai) {
        const int row0 = m_blk + wm + (ai>>2)*64 + (ai&3)*16 + quad*4;
        #pragma unroll
        for (int bi = 0; bi < 4; ++bi) {
            const int col = n_blk + wn + (bi>>1)*32 + (bi&1)*16 + l15;
            if constexpr (F32OUT) {
                #pragma unroll
                for (int r = 0; r < 4; ++r)
                    ((float*)Cv)[(size_t)(row0 + r)*N + col] = acc[ai][bi][r];
            } else {
                #pragma unroll
                for (int r = 0; r < 4; ++r)
                    ((bf16*)Cv)[(size_t)(row0 + r)*N + col] = (bf16)acc[ai][bi][r];
            }
        }
    }
}

// ---------------------------------------------------------------------------
// Per-head LayerNorm + RoPE, in place on bf16 workspace. One wave per
// (token, head); lane j holds dims j and j+64 (the RoPE pair). w is fp32.
// Fused Q+K launch: ids < NTOK*NH are Q rows (qb, qw_, NH); the rest are K
// rows (kb, kw_, NKV). Boundary NTOK*NH/4 = 32768 is block-aligned.
// ---------------------------------------------------------------------------
__global__ __launch_bounds__(256)
void ln_rope2(bf16* __restrict__ qb, bf16* __restrict__ kb,
              const float* __restrict__ qw_, const float* __restrict__ kw_,
              const int* __restrict__ pos)
{
    int id = blockIdx.x * 4 + (threadIdx.x >> 6);
    const int lane = threadIdx.x & 63;

    bf16* buf; const float* w; int nh;
    if (id < NTOK*NH) { buf = qb; w = qw_; nh = NH; }
    else              { id -= NTOK*NH; buf = kb; w = kw_; nh = NKV; }

    const int t  = id / nh;
    const int hh = id - t * nh;

    bf16* p = buf + (size_t)t * nh * HD + hh * HD;
    float x1 = (float)p[lane];
    float x2 = (float)p[lane + 64];

    float s1 = x1 + x2, s2 = x1*x1 + x2*x2;
    #pragma unroll
    for (int m = 1; m < 64; m <<= 1) {
        s1 += __shfl_xor(s1, m);
        s2 += __shfl_xor(s2, m);
    }
    const float mean = s1 * (1.0f/128.0f);
    const float var  = s2 * (1.0f/128.0f) - mean*mean;
    const float rs   = rsqrtf(fmaxf(var, 0.0f) + 1e-5f);

    const float w1 = w[hh*HD + lane];
    const float w2 = w[hh*HD + lane + 64];
    const float xn1 = (x1 - mean) * rs * w1;
    const float xn2 = (x2 - mean) * rs * w2;

    const int s = t & (SEQ - 1);
    // inv_freq = 10000^(-lane/64) = exp(-lane * ln(10000)/64)
    const float ang = (float)pos[s] * __expf(-(float)lane * (9.210340371976184f/64.0f));
    const float c = cosf(ang), sn = sinf(ang);

    p[lane]      = (bf16)(xn1 * c - xn2 * sn);
    p[lane + 64] = (bf16)(xn2 * c + xn1 * sn);
}

// ---------------------------------------------------------------------------
// Flash attention, causal, GQA — 8-wave swapped-operand structure (m214 port)
//   block = 256 q rows (8 waves x 32), KV tile = 64, mfma_f32_32x32x16_bf16
//   QK^T computed as mfma(K,Q)  -> S^T : q on lane&31, kv on regs
//   PV   computed as mfma(Vt,P) -> O^T : q on lane&31, d  on regs
//   => softmax max/sum, O-rescale, l-division all lane-local; P never
//      touches LDS (cross-half exchange via shfl_xor(.,32), T12)
//   K and V^T staged to XOR-swizzled LDS (T2), double-buffered, reg-staged
//   issue-early/write-late (T14), one barrier per tile, setprio on MFMA (T5),
//   defer-max THR=8 in log2 domain (T13).
//   Causal balance: qt mirrored on batch so every CU's 2 resident blocks sum
//   to the same kv work (36 tile-units).
//   NOTE: permlane32_swap attempt (r3) FAILED correctness — swap-direction
//   semantics unverified; exchange uses harness-verified shfl_xor form.
// ---------------------------------------------------------------------------
struct StReg { bf16x8 k0, k1, v0, v1; };

__device__ __forceinline__ StReg stage_load(const bf16* kgp, const bf16* vgp, int t)
{
    StReg r;
    const size_t ko = (size_t)t * 64 * KVDIM;
    r.k0 = *(const bf16x8*)(kgp + ko);
    r.k1 = *(const bf16x8*)(kgp + ko + 64);
    r.v0 = *(const bf16x8*)(vgp + t*64);
    r.v1 = *(const bf16x8*)(vgp + t*64 + 32);
    return r;
}

__device__ __forceinline__ void stage_write(bf16* dk, bf16* dv, const StReg& r,
                                            int krow, int kcb, int vrow, int vcb)
{
    // K: [64 rows][128 cols] bf16, row stride 256B, byte ^= (row&7)<<4
    *(bf16x8*)((char*)dk + krow*256 + ( kcb        ^ ((krow&7)<<4))) = r.k0;
    *(bf16x8*)((char*)dk + krow*256 + ((kcb + 128) ^ ((krow&7)<<4))) = r.k1;
    // V^T: [128 d][64 kv] bf16, row stride 128B, same involution
    *(bf16x8*)((char*)dv + vrow*128 + ( vcb        ^ ((vrow&7)<<4))) = r.v0;
    *(bf16x8*)((char*)dv + vrow*128 + ((vcb +  64) ^ ((vrow&7)<<4))) = r.v1;
}

__device__ __forceinline__ unsigned pk2(float x, float y)
{
    union { bf16 h[2]; unsigned u; } c;
    c.h[0] = (bf16)x; c.h[1] = (bf16)y;
    return c.u;
}

__global__ __launch_bounds__(512, 2)
void attn_fa(bf16* __restrict__ qob,        // [NTOK][QDIM], Q in / O out
             const bf16* __restrict__ kbp,  // [NTOK][KVDIM]
             const bf16* __restrict__ vtb)  // [B][KVDIM][SEQ]  (V transposed)
{
    __shared__ bf16 sK[2][64*128];   // 32 KB, swizzled
    __shared__ bf16 sV[2][128*64];   // 32 KB, swizzled

    const int tid  = threadIdx.x;
    const int wave = tid >> 6;
    const int lane = tid & 63;
    const int l31  = lane & 31;
    const int hi   = lane >> 5;

    const int b  = blockIdx.z;       // batch (2)
    // mirror qt on batch: co-resident block pair (x,b=0)+(x,b=1) has constant
    // total kv work -> balanced per-CU makespan under round-robin dispatch
    const int qt = b ? (gridDim.x - 1 - blockIdx.x) : blockIdx.x;
    const int h  = blockIdx.y;       // q head (32)
    const int hk = h >> 2;
    const int qbase = qt * 256;
    const int qw    = qbase + wave * 32;   // wave's first q row
    const int qrow  = qw + l31;            // this lane's q row

    // ---- Q fragments (B operand): lane holds Q[qrow][ks*16 + hi*8 + 0..7]
    bf16x8 qf[8];
    {
        const bf16* qp = qob + (size_t)(b*SEQ + qrow)*QDIM + h*HD + hi*8;
        #pragma unroll
        for (int ks = 0; ks < 8; ++ks)
            qf[ks] = *(const bf16x8*)(qp + ks*16);
    }

    f32x16 oacc[4] = {};             // O^T: q = lane&31, d = dblk*32 + crow(reg,hi)
    float m_i = NEGBIG, l_i = 0.0f;

    // staging geometry (512 threads, 2 x 16B per tile for each of K, V^T)
    const int krow = tid >> 3;             // 0..63
    const int kcb  = (tid & 7) * 16;       // byte col 0..112
    const int vrow = tid >> 2;             // 0..127
    const int vcb  = (tid & 3) * 16;       // byte col 0..48
    const bf16* kgp = kbp + (size_t)(b*SEQ + krow)*KVDIM + hk*HD + (tid & 7)*8;
    const bf16* vgp = vtb + ((size_t)(b*NKV + hk)*HD + vrow)*SEQ + (tid & 3)*8;

    const int ntiles = qt*4 + 4;
    const float SC = 0.08838834764831845f * 1.4426950408889634f;  // scale*log2e
    const int kx = (l31 & 7) << 4;         // read-side swizzle (rows ≡ l31 mod 8)

    // prologue: stage tile 0 into buffer 0
    {
        StReg r = stage_load(kgp, vgp, 0);
        stage_write(sK[0], sV[0], r, krow, kcb, vrow, vcb);
    }
    __syncthreads();

    int cur = 0;
    for (int t = 0; t < ntiles; ++t) {
        const int kv0 = t * 64;
        const bool hn = (t + 1 < ntiles);
        StReg nx;
        if (hn) nx = stage_load(kgp, vgp, t + 1);   // issue early (T14)

        if (kv0 <= qw + 31) {                       // skip fully-masked tiles
            // ---- S^T = K·Q^T : 16 mfma, kv on regs, q on lanes
            f32x16 sa0 = {}, sa1 = {};
            const char* kl = (const char*)sK[cur];
            __builtin_amdgcn_s_setprio(1);
            #pragma unroll
            for (int ks = 0; ks < 8; ++ks) {
                const int cb = ks*32 + hi*16;
                bf16x8 k0 = *(const bf16x8*)(kl + l31*256        + (cb ^ kx));
                bf16x8 k1 = *(const bf16x8*)(kl + l31*256 + 8192 + (cb ^ kx));
                sa0 = __builtin_amdgcn_mfma_f32_32x32x16_bf16(k0, qf[ks], sa0, 0, 0, 0);
                sa1 = __builtin_amdgcn_mfma_f32_32x32x16_bf16(k1, qf[ks], sa1, 0, 0, 0);
            }
            __builtin_amdgcn_s_setprio(0);

            // ---- scale (log2 domain) + causal mask on diagonal tiles
            float s[32];
            #pragma unroll
            for (int r = 0; r < 16; ++r) { s[r] = sa0[r]*SC; s[16+r] = sa1[r]*SC; }
            if (kv0 + 63 > qw) {
                #pragma unroll
                for (int j = 0; j < 32; ++j) {
                    const int kv = kv0 + (j>>4)*32 + (j&3) + ((j>>2)&3)*8 + hi*4;
                    if (kv > qrow) s[j] = NEGBIG;
                }
            }

            // ---- online softmax, lane-local (partner lane = other 32 kv)
            float mt = s[0];
            #pragma unroll
            for (int j = 1; j < 32; ++j) mt = fmaxf(mt, s[j]);
            mt = fmaxf(mt, __shfl_xor(mt, 32));
            if (__any(mt > m_i + 8.0f)) {           // defer-max (T13)
                const float mnew = fmaxf(m_i, mt);
                const float al = exp2f(m_i - mnew);
                m_i = mnew; l_i *= al;
                #pragma unroll
                for (int d = 0; d < 4; ++d)
                    #pragma unroll
                    for (int r = 0; r < 16; ++r) oacc[d][r] *= al;
            }
            float p[32]; float sum = 0.0f;
            #pragma unroll
            for (int j = 0; j < 32; ++j) { p[j] = exp2f(s[j] - m_i); sum += p[j]; }
            sum += __shfl_xor(sum, 32);
            l_i += sum;

            // ---- P -> bf16 B-fragments, cross-half exchange (T12 w/ shfl)
            // pb[ks][j] = P[q][ks*16 + hi*8 + j]; src idx base c = (ks>>1)*16+(ks&1)*8
            bf16x8 pb[4];
            #pragma unroll
            for (int ks = 0; ks < 4; ++ks) {
                const int c = (ks>>1)*16 + (ks&1)*8;
                const unsigned a0 = pk2(p[c+0], p[c+1]);
                const unsigned a1 = pk2(p[c+2], p[c+3]);
                const unsigned b0 = pk2(p[c+4], p[c+5]);
                const unsigned b1 = pk2(p[c+6], p[c+7]);
                const unsigned r0 = (unsigned)__shfl_xor((int)(hi ? a0 : b0), 32);
                const unsigned r1 = (unsigned)__shfl_xor((int)(hi ? a1 : b1), 32);
                union { unsigned u[4]; bf16x8 v; } fr;
                fr.u[0] = hi ? r0 : a0;
                fr.u[1] = hi ? r1 : a1;
                fr.u[2] = hi ? b0 : r0;
                fr.u[3] = hi ? b1 : r1;
                pb[ks] = fr.v;
            }

            // ---- O^T += V^T·P : 16 mfma, d on regs, q on lanes
            const char* vl = (const char*)sV[cur];
            __builtin_amdgcn_s_setprio(1);
            #pragma unroll
            for (int d = 0; d < 4; ++d) {
                #pragma unroll
                for (int ks = 0; ks < 4; ++ks) {
                    const int cb = ks*32 + hi*16;
                    bf16x8 vf = *(const bf16x8*)(vl + (d*32 + l31)*128 + (cb ^ kx));
                    oacc[d] = __builtin_amdgcn_mfma_f32_32x32x16_bf16(vf, pb[ks], oacc[d], 0, 0, 0);
                }
            }
            __builtin_amdgcn_s_setprio(0);
        }

        if (hn) stage_write(sK[cur^1], sV[cur^1], nx, krow, kcb, vrow, vcb);
        __syncthreads();
        cur ^= 1;
    }

    // ---- epilogue: O/l back into qob (q = lane&31 -> lane-local l)
    const float inv = 1.0f / l_i;
    bf16* op = qob + (size_t)(b*SEQ + qrow)*QDIM + h*HD + hi*4;
    #pragma unroll
    for (int d = 0; d < 4; ++d) {
        #pragma unroll
        for (int q2 = 0; q2 < 4; ++q2) {
            bf16x4 pk;
            #pragma unroll
            for (int r = 0; r < 4; ++r) pk[r] = (bf16)(oacc[d][q2*4 + r] * inv);
            *(bf16x4*)(op + d*32 + q2*8) = pk;   // d = d*32 + q2*8 + hi*4 + r
        }
    }
}

// ---------------------------------------------------------------------------
extern "C" void kernel_launch(void* const* d_in, const int* in_sizes, int n_in,
                              void* d_out, int out_size, void* d_ws, size_t ws_size,
                              hipStream_t stream)
{
    // fp32 inputs per the reference dtypes
    const float* hidden = (const float*)d_in[0];
    const int*   pos    = (const int*)d_in[1];
    const float* wq     = (const float*)d_in[2];
    const float* wk     = (const float*)d_in[3];
    const float* wv     = (const float*)d_in[4];
    const float* wo     = (const float*)d_in[5];
    const float* qw     = (const float*)d_in[6];
    const float* kw     = (const float*)d_in[7];

    // bf16 workspace, 128 MB total (wo reuses the dead wq slot)
    bf16* hb   = (bf16*)d_ws;                          // [NTOK][HIDDEN]  32MB
    bf16* wqb  = hb   + (size_t)NTOK*HIDDEN;           // [QDIM][HIDDEN]  32MB (wq, then wo)
    bf16* wkb  = wqb  + (size_t)QDIM*HIDDEN;           // [KVDIM][HIDDEN]  8MB
    bf16* wvb  = wkb  + (size_t)KVDIM*HIDDEN;          // [KVDIM][HIDDEN]  8MB (contiguous after wkb!)
    bf16* qbuf = wvb  + (size_t)KVDIM*HIDDEN;          // [NTOK][QDIM]    32MB (Q, then attn out)
    bf16* kbuf = qbuf + (size_t)NTOK*QDIM;             // [NTOK][KVDIM]    8MB
    bf16* vtb  = kbuf + (size_t)NTOK*KVDIM;            // [B][KVDIM][SEQ]  8MB
    float* out = (float*)d_out;                        // fp32 output

    const dim3 blk(256);

    // fp32 -> bf16 pre-conversion, single fused launch (hidden, wq, wk, wv)
    cvt4<<<dim3(20480), blk, 0, stream>>>(hidden, hb, wq, wqb, wk, wkb, wv, wvb);

    // Q-proj: 4096x4096x4096 -> 8-phase 256^2 kernel (grid 16x16 = 256 blocks)
    gemm256<false><<<dim3(QDIM/256, NTOK/256), dim3(512), 0, stream>>>(hb, wqb, qbuf, NTOK, QDIM, HIDDEN);

    // K+V proj merged: B = [wk; wv] (contiguous, 2048 rows), grid 16x32 = 512
    // blocks = 2 blocks/CU. Epilogue splits: cols<1024 -> kbuf, else vtb^T.
    gemm_bt<3><<<dim3((2*KVDIM)/128, NTOK/128), blk, 0, stream>>>(hb, wkb, kbuf, vtb, NTOK, 2*KVDIM, HIDDEN);

    // wq slot is dead after the Q-GEMM; stream order makes this safe
    cvt_f32_bf16<<<dim3(QDIM*HIDDEN/2048), blk, 0, stream>>>(wo, wqb);

    // LN+RoPE for Q and K in one launch (boundary is block-aligned)
    ln_rope2<<<dim3(NTOK*(NH+NKV)/4), blk, 0, stream>>>(qbuf, kbuf, qw, kw, pos);

    attn_fa<<<dim3(SEQ/256, NH, BATCH), dim3(512), 0, stream>>>(qbuf, kbuf, vtb);

    // out-proj: 4096x4096x4096, fp32 out -> 8-phase kernel
    gemm256<true><<<dim3(QDIM/256, NTOK/256), dim3(512), 0, stream>>>(qbuf, wqb, out, NTOK, QDIM, HIDDEN);
}